// Round 5
// baseline (239.940 us; speedup 1.0000x reference)
//
#include <hip/hip_runtime.h>
#include <hip/hip_bf16.h>

typedef unsigned int  u32;
typedef unsigned short u16;
typedef __attribute__((ext_vector_type(8))) short bf16x8;
typedef __attribute__((ext_vector_type(4))) float f32x4;
typedef __attribute__((ext_vector_type(4))) u32 u32x4;

#define NPIX 65536

// ---------------- ws byte offsets ----------------
constexpr size_t SIG   = 0;                   // 4 floats
constexpr size_t B1OFF = 256;                 // 512 f32
constexpr size_t B2OFF = B1OFF + 2048;        // 256 f32
constexpr size_t WC1   = B2OFF + 1024;        // 128x576 bf16
constexpr size_t WC2   = WC1 + 147456;        // 64x1152
constexpr size_t WF1   = WC2 + 147456;        // 128x1152
constexpr size_t WF2   = WF1 + 294912;        // 64x1152
constexpr size_t WP1   = WF2 + 147456;        // 512x64
constexpr size_t WP2   = WP1 + 65536;         // 256x128
constexpr size_t XB    = WP2 + 65536;         // 65536x64 bf16 (8 MB)
constexpr size_t HBUF  = XB + 8388608;        // 65536x128 bf16 (16 MB)
constexpr size_t QKVS2 = HBUF + 16777216;     // 65536x256 bf16 (32 MB)
constexpr size_t XC    = QKVS2 + 33554432;    // 65536x128 bf16 (16 MB) concat buf
constexpr size_t QKVS1 = XC + 16777216;       // 65536x512 bf16 (64 MB)
constexpr size_t Y1    = QKVS1;               // alias: y1 lives after qkvs1 dead
constexpr size_t TBUF  = QKVS1 + 16777216;    // alias: t
constexpr size_t GRAM  = QKVS1 + 67108864;    // 4 x 128x128 f32 (256 KB)

// ---------------- helpers ----------------
__device__ __forceinline__ float gelu_f(float v) {
    // exact-erf gelu, A&S 7.1.26 minimax (|erf err| <= 1.5e-7), branchless
    float xa = fabsf(v) * 0.70710678118654752f;
    float t  = __fdividef(1.0f, fmaf(0.3275911f, xa, 1.0f));
    float poly = t * fmaf(t, fmaf(t, fmaf(t, fmaf(t, 1.061405429f, -1.453152027f),
                   1.421413741f), -0.284496736f), 0.254829592f);
    float erfv = 1.0f - poly * __expf(-xa * xa);
    erfv = copysignf(erfv, v);
    return 0.5f * v * (1.0f + erfv);
}
__device__ __forceinline__ u16 f2bf(float f) {
    __hip_bfloat16 b = __float2bfloat16(f);
    return *reinterpret_cast<u16*>(&b);
}
__device__ __forceinline__ float blo(u32 u) {
    union { u32 i; float f; } x; x.i = u << 16; return x.f;
}
__device__ __forceinline__ float bhi(u32 u) {
    union { u32 i; float f; } x; x.i = u & 0xffff0000u; return x.f;
}
__device__ __forceinline__ u32 packbf(float a, float b) {
    return (u32)f2bf(a) | ((u32)f2bf(b) << 16);
}
__device__ __forceinline__ void g2l16(const void* g, void* l) {
    __builtin_amdgcn_global_load_lds(
        (const __attribute__((address_space(1))) u32*)g,
        (__attribute__((address_space(3))) u32*)l, 16, 0, 0);
}

// ---------------- block reduction ----------------
__device__ float block_sum(float vv, float* red) {
    #pragma unroll
    for (int m = 1; m < 64; m <<= 1) vv += __shfl_xor(vv, m);
    int tid = threadIdx.x;
    __syncthreads();
    if ((tid & 63) == 0) red[tid >> 6] = vv;
    __syncthreads();
    return red[0] + red[1] + red[2] + red[3];
}

// ---------------- Gram matrix: G_w = W_w * W_w^T (tiled, parallel) ----------------
__global__ __launch_bounds__(256)
void gram_kernel(const float* __restrict__ cW1, const float* __restrict__ cW2,
                 const float* __restrict__ fW1, const float* __restrict__ fW2,
                 float* __restrict__ Gall) {
    int bid = blockIdx.x;
    const float* W; int O, K, wsel, tile;
    if (bid < 64)       { W = cW1; O = 128; K = 576;  wsel = 0; tile = bid; }
    else if (bid < 80)  { W = cW2; O = 64;  K = 1152; wsel = 1; tile = bid - 64; }
    else if (bid < 144) { W = fW1; O = 128; K = 1152; wsel = 2; tile = bid - 80; }
    else                { W = fW2; O = 64;  K = 1152; wsel = 3; tile = bid - 144; }
    int ntiles = O >> 4;
    int ti0 = (tile / ntiles) << 4, tj0 = (tile % ntiles) << 4;
    __shared__ float Wi[16][33], Wj[16][33];
    int tid = threadIdx.x;
    int ti = tid >> 4, tj = tid & 15;
    int r = tid >> 5, c = tid & 31;
    float acc = 0.f;
    for (int k0 = 0; k0 < K; k0 += 32) {
        Wi[r][c]     = W[(size_t)(ti0 + r) * K + k0 + c];
        Wi[r + 8][c] = W[(size_t)(ti0 + r + 8) * K + k0 + c];
        Wj[r][c]     = W[(size_t)(tj0 + r) * K + k0 + c];
        Wj[r + 8][c] = W[(size_t)(tj0 + r + 8) * K + k0 + c];
        __syncthreads();
        #pragma unroll
        for (int k = 0; k < 32; ++k)
            acc += Wi[ti][k] * Wj[tj][k];
        __syncthreads();
    }
    Gall[wsel * 16384 + (ti0 + ti) * 128 + (tj0 + tj)] = acc;
}

// ---------------- power iteration on G (4 blocks) ----------------
__global__ __launch_bounds__(256)
void power_kernel(const float* __restrict__ Gall, float* __restrict__ sig) {
    int wsel = blockIdx.x;
    const float* G = Gall + wsel * 16384;
    const int O = (wsel == 0 || wsel == 2) ? 128 : 64;
    __shared__ float u[128], t[128], red[4];
    int tid = threadIdx.x;
    if (tid < O) u[tid] = 1.0f / sqrtf((float)O);
    __syncthreads();
    for (int it = 0; it < 3; ++it) {
        if (tid < O) {
            float s = 0.f;
            const float4* gr = reinterpret_cast<const float4*>(G + (size_t)tid * 128);
            for (int j = 0; j < O / 4; ++j) {
                float4 g = gr[j];
                s += g.x * u[4*j] + g.y * u[4*j+1] + g.z * u[4*j+2] + g.w * u[4*j+3];
            }
            t[tid] = s;
        }
        __syncthreads();
        float loc = (tid < O) ? t[tid] * t[tid] : 0.f;
        float nt = sqrtf(block_sum(loc, red));
        if (it == 2) {
            float locd = (tid < O) ? u[tid] * t[tid] : 0.f;
            float dot = block_sum(locd, red);
            if (tid == 0) sig[wsel] = nt / sqrtf(dot + 1e-24f);
        } else {
            if (tid < O) u[tid] = t[tid] / (nt + 1e-12f);
            __syncthreads();
        }
    }
}

// ---------------- conv weight prep ----------------
__global__ __launch_bounds__(256)
void prep_conv_w(const float* __restrict__ cW1, const float* __restrict__ cW2,
                 const float* __restrict__ fW1, const float* __restrict__ fW2,
                 const float* __restrict__ sig,
                 u16* wc1, u16* wc2, u16* wf1, u16* wf2) {
    int wsel = blockIdx.y;
    const float* src; u16* dst; int O, C;
    switch (wsel) {
        case 0:  src = cW1; dst = wc1; O = 128; C = 64;  break;
        case 1:  src = cW2; dst = wc2; O = 64;  C = 128; break;
        case 2:  src = fW1; dst = wf1; O = 128; C = 128; break;
        default: src = fW2; dst = wf2; O = 64;  C = 128; break;
    }
    int idx = blockIdx.x * 256 + threadIdx.x;
    if (idx >= O * C * 9) return;
    int o = idx / (C * 9);
    int rem = idx - o * (C * 9);
    int ci = rem / 9, tap = rem - ci * 9;
    float v = src[idx] / sig[wsel];
    dst[(size_t)o * (C * 9) + tap * C + ci] = f2bf(v);
}

// ---------------- projection weight/bias prep ----------------
__global__ __launch_bounds__(256)
void prep_proj(const float* q1W, const float* k1W, const float* v1W, const float* s1W,
               const float* q2W, const float* k2W, const float* v2W, const float* s2W,
               const float* q1b, const float* k1b, const float* v1b, const float* s1b,
               const float* q2b, const float* k2b, const float* v2b, const float* s2b,
               u16* wp1, u16* wp2, float* b1, float* b2) {
    const float* W1[4] = {q1W, k1W, v1W, s1W};
    const float* W2[4] = {q2W, k2W, v2W, s2W};
    const float* Bb1[4] = {q1b, k1b, v1b, s1b};
    const float* Bb2[4] = {q2b, k2b, v2b, s2b};
    int idx = blockIdx.x * 256 + threadIdx.x;
    if (idx < 32768) {
        int w = idx >> 13, r = idx & 8191;
        wp1[(size_t)w * 8192 + r] = f2bf(W1[w][r]);
    } else if (idx < 65536) {
        int j = idx - 32768; int w = j >> 13, r = j & 8191;
        wp2[(size_t)w * 8192 + r] = f2bf(W2[w][r]);
    } else if (idx < 66048) {
        int j = idx - 65536; int w = j >> 7; b1[j] = Bb1[w][j & 127];
    } else if (idx < 66304) {
        int j = idx - 66048; int w = j >> 6; b2[j] = Bb2[w][j & 63];
    }
}

// ---------------- x NCHW f32 -> [pix][64] bf16 ----------------
__global__ __launch_bounds__(256)
void convert_x(const float* __restrict__ x, u16* __restrict__ xb) {
    __shared__ float tile[64][65];
    int b = blockIdx.x >> 6, y = blockIdx.x & 63;
    int tid = threadIdx.x;
    #pragma unroll
    for (int i = 0; i < 16; ++i) {
        int c = (tid >> 6) + i * 4;
        tile[c][tid & 63] = x[(((size_t)b * 64 + c) << 12) + (y << 6) + (tid & 63)];
    }
    __syncthreads();
    #pragma unroll
    for (int i = 0; i < 16; ++i) {
        int idx = tid + i * 256;
        int p = idx >> 6, c = idx & 63;
        xb[(((size_t)b << 12) + (y << 6) + p) * 64 + c] = f2bf(tile[c][p]);
    }
}

// ---------------- bf16 MFMA GEMM, implicit im2col, dbuf + XOR-swizzled LDS ----------------
// LDS tiles [rows][32] bf16; 16B chunk c of row r stored at chunk c ^ ((r>>1)&3).
// global_load_lds writes linearly -> inverse-swizzle the per-lane GLOBAL source
// chunk; ds_read applies the same XOR (involution, rule both-sides-or-neither).
template<int TAPS, int CC, int BN, int OUTM>
__global__ __launch_bounds__(256)
void mm_kernel(const u16* __restrict__ A, const u16* __restrict__ Bw,
               const float* __restrict__ bias, void* __restrict__ Cout,
               int ostride, int ocol0, int do_gelu) {
    constexpr int K = CC * TAPS;
    constexpr int NSTEP = K / 32;
    constexpr int NF = BN / 32;
    constexpr int HN = BN / 2;
    __shared__ u16 Als[2][128 * 32];
    __shared__ u16 Bls[2][BN * 32];
    const int tid = threadIdx.x;
    const int w = tid >> 6;
    const int lane = tid & 63;
    const int m0 = blockIdx.x * 128;
    const int nt0 = blockIdx.y * BN;
    const int wm = w >> 1, wn = w & 1;
    // staging: lane covers LDS row (tid>>2)(+64r), chunk slot (tid&3);
    // fetch global chunk (slot ^ key(row)), key(row) = (row>>1)&3 = (tid>>3)&3
    const int csrc = (((tid & 3) ^ ((tid >> 3) & 3)) << 3);

    f32x4 acc[4][NF];
    #pragma unroll
    for (int i = 0; i < 4; ++i)
        #pragma unroll
        for (int j = 0; j < NF; ++j) {
            f32x4 z = {0.f, 0.f, 0.f, 0.f};
            acc[i][j] = z;
        }

    auto stage = [&](int kt, int buf) {
        const int kk = kt * 32;
        int tap = 0, ci0 = kk;
        if (TAPS == 9) { tap = kk / CC; ci0 = kk - tap * CC; }
        const int dy = tap / 3 - 1, dx2 = tap % 3 - 1;
        #pragma unroll
        for (int r = 0; r < 2; ++r) {
            int row = (tid >> 2) + r * 64;
            int m = m0 + row;
            int q;
            if (TAPS == 9) {
                int yy = ((m >> 6) & 63) + dy; yy = yy < 0 ? 0 : (yy > 63 ? 63 : yy);
                int xx = (m & 63) + dx2;       xx = xx < 0 ? 0 : (xx > 63 ? 63 : xx);
                q = (m & ~4095) | (yy << 6) | xx;
            } else q = m;
            const u16* g = A + (size_t)q * CC + ci0 + csrc;
            g2l16(g, &Als[buf][w * 512 + r * 2048]);
        }
        #pragma unroll
        for (int r = 0; r < BN / 64; ++r) {
            int row = (tid >> 2) + r * 64;
            const u16* g = Bw + (size_t)(nt0 + row) * K + kk + csrc;
            g2l16(g, &Bls[buf][w * 512 + r * 2048]);
        }
    };

    stage(0, 0);
    __syncthreads();              // implicit vmcnt(0): tile 0 landed

    #pragma unroll 2
    for (int kt = 0; kt < NSTEP; ++kt) {
        const int cur = kt & 1;
        if (kt + 1 < NSTEP) stage(kt + 1, cur ^ 1);   // prefetch under compute
        bf16x8 af[4];
        #pragma unroll
        for (int mf = 0; mf < 4; ++mf) {
            int R = wm * 64 + mf * 16 + (lane & 15);
            int C = ((lane >> 4) ^ ((R >> 1) & 3)) << 3;
            af[mf] = *reinterpret_cast<const bf16x8*>(&Als[cur][R * 32 + C]);
        }
        #pragma unroll
        for (int nf = 0; nf < NF; ++nf) {
            int Rb = wn * HN + nf * 16 + (lane & 15);
            int Cb = ((lane >> 4) ^ ((Rb >> 1) & 3)) << 3;
            bf16x8 bfv = *reinterpret_cast<const bf16x8*>(&Bls[cur][Rb * 32 + Cb]);
            #pragma unroll
            for (int mf = 0; mf < 4; ++mf)
                acc[mf][nf] = __builtin_amdgcn_mfma_f32_16x16x32_bf16(
                    af[mf], bfv, acc[mf][nf], 0, 0, 0);
        }
        __syncthreads();          // drains prefetch vmcnt + guards buf reuse
    }

    #pragma unroll
    for (int mf = 0; mf < 4; ++mf) {
        int mrow = m0 + wm * 64 + mf * 16 + (lane >> 4) * 4;
        #pragma unroll
        for (int nf = 0; nf < NF; ++nf) {
            int col = nt0 + wn * HN + nf * 16 + (lane & 15);
            float bv = bias[col];
            if (OUTM == 0) {
                u16* Co = (u16*)Cout;
                #pragma unroll
                for (int j = 0; j < 4; ++j) {
                    float v = acc[mf][nf][j] + bv;
                    if (do_gelu) v = gelu_f(v);
                    Co[(size_t)(mrow + j) * ostride + ocol0 + col] = f2bf(v);
                }
            } else {
                float* Co = (float*)Cout;
                int b = m0 >> 12;
                int pixb = (mrow & 4095);
                f32x4 vv;
                #pragma unroll
                for (int j = 0; j < 4; ++j) {
                    float v = acc[mf][nf][j] + bv;
                    vv[j] = gelu_f(v);
                }
                *reinterpret_cast<f32x4*>(&Co[((size_t)(b * 64 + col)) * 4096 + pixb]) = vv;
            }
        }
    }
}

// ---------------- attention layer 1: heads=8, d=16, 8ch/lane ----------------
// qkvs row = 256 u32 (Q 0..63, K 64..127, V 128..191, S 192..255)
__global__ __launch_bounds__(256)
void attn1_kernel(const u16* __restrict__ qkvs, u16* __restrict__ h) {
    const int tid = threadIdx.x;
    const int l16 = tid & 15;
    const int n = blockIdx.x * 16 + (tid >> 4);
    const int y = (n >> 6) & 63, x = n & 63;
    const u32* qk = (const u32*)qkvs;
    const int nbase = (n << 8) + l16 * 4;

    u32x4 qp = *(const u32x4*)(qk + nbase);
    float q[8];
    #pragma unroll
    for (int i = 0; i < 4; ++i) { q[2*i] = blo(qp[i]); q[2*i+1] = bhi(qp[i]); }

    float al[9];
    float mx = -1e30f;
    #pragma unroll
    for (int e = 0; e < 9; ++e) {
        const int dy = e / 3 - 1, dx = e % 3 - 1;
        const bool valid = (unsigned)(y + dy) < 64u && (unsigned)(x + dx) < 64u;
        const int off = valid ? ((dy * 64 + dx) << 8) : 0;
        u32x4 kp = *(const u32x4*)(qk + nbase + off + 64);
        float p = 0.f;
        #pragma unroll
        for (int i = 0; i < 4; ++i) {
            p = fmaf(q[2*i],   blo(kp[i]), p);
            p = fmaf(q[2*i+1], bhi(kp[i]), p);
        }
        p += __shfl_xor(p, 1);       // head = 16ch = 2 lanes
        al[e] = valid ? p * 0.25f : -1e30f;
        mx = fmaxf(mx, al[e]);
    }
    float s = 0.f;
    #pragma unroll
    for (int e = 0; e < 9; ++e) { al[e] = __expf(al[e] - mx); s += al[e]; }

    float o[8] = {0.f, 0.f, 0.f, 0.f, 0.f, 0.f, 0.f, 0.f};
    #pragma unroll
    for (int e = 0; e < 9; ++e) {
        const int dy = e / 3 - 1, dx = e % 3 - 1;
        const bool valid = (unsigned)(y + dy) < 64u && (unsigned)(x + dx) < 64u;
        const int off = valid ? ((dy * 64 + dx) << 8) : 0;
        u32x4 vp = *(const u32x4*)(qk + nbase + off + 128);
        const float a = al[e];
        #pragma unroll
        for (int i = 0; i < 4; ++i) {
            o[2*i]   = fmaf(a, blo(vp[i]), o[2*i]);
            o[2*i+1] = fmaf(a, bhi(vp[i]), o[2*i+1]);
        }
    }
    const float r = __fdividef(1.0f, s + 1e-16f);
    u32x4 sp = *(const u32x4*)(qk + nbase + 192);
    u32x4 res;
    #pragma unroll
    for (int i = 0; i < 4; ++i) {
        float h0 = gelu_f(fmaf(o[2*i],   r, blo(sp[i])));
        float h1 = gelu_f(fmaf(o[2*i+1], r, bhi(sp[i])));
        res[i] = packbf(h0, h1);
    }
    *(u32x4*)((u32*)h + (n << 6) + l16 * 4) = res;
}

// ---------------- attention layer 2: heads=1, d=64, 8ch/lane ----------------
// qkvs row = 128 u32 (Q 0..31, K 32..63, V 64..95, S 96..127); out -> xc cols 64..127
__global__ __launch_bounds__(256)
void attn2_kernel(const u16* __restrict__ qkvs, u16* __restrict__ xc) {
    const int tid = threadIdx.x;
    const int l8 = tid & 7;
    const int n = blockIdx.x * 32 + (tid >> 3);
    const int y = (n >> 6) & 63, x = n & 63;
    const u32* qk = (const u32*)qkvs;
    const int nbase = (n << 7) + l8 * 4;

    u32x4 qp = *(const u32x4*)(qk + nbase);
    float q[8];
    #pragma unroll
    for (int i = 0; i < 4; ++i) { q[2*i] = blo(qp[i]); q[2*i+1] = bhi(qp[i]); }

    float al[9];
    float mx = -1e30f;
    #pragma unroll
    for (int e = 0; e < 9; ++e) {
        const int dy = e / 3 - 1, dx = e % 3 - 1;
        const bool valid = (unsigned)(y + dy) < 64u && (unsigned)(x + dx) < 64u;
        const int off = valid ? ((dy * 64 + dx) << 7) : 0;
        u32x4 kp = *(const u32x4*)(qk + nbase + off + 32);
        float p = 0.f;
        #pragma unroll
        for (int i = 0; i < 4; ++i) {
            p = fmaf(q[2*i],   blo(kp[i]), p);
            p = fmaf(q[2*i+1], bhi(kp[i]), p);
        }
        p += __shfl_xor(p, 1);
        p += __shfl_xor(p, 2);
        p += __shfl_xor(p, 4);       // head = 64ch = 8 lanes
        al[e] = valid ? p * 0.125f : -1e30f;
        mx = fmaxf(mx, al[e]);
    }
    float s = 0.f;
    #pragma unroll
    for (int e = 0; e < 9; ++e) { al[e] = __expf(al[e] - mx); s += al[e]; }

    float o[8] = {0.f, 0.f, 0.f, 0.f, 0.f, 0.f, 0.f, 0.f};
    #pragma unroll
    for (int e = 0; e < 9; ++e) {
        const int dy = e / 3 - 1, dx = e % 3 - 1;
        const bool valid = (unsigned)(y + dy) < 64u && (unsigned)(x + dx) < 64u;
        const int off = valid ? ((dy * 64 + dx) << 7) : 0;
        u32x4 vp = *(const u32x4*)(qk + nbase + off + 64);
        const float a = al[e];
        #pragma unroll
        for (int i = 0; i < 4; ++i) {
            o[2*i]   = fmaf(a, blo(vp[i]), o[2*i]);
            o[2*i+1] = fmaf(a, bhi(vp[i]), o[2*i+1]);
        }
    }
    const float r = __fdividef(1.0f, s + 1e-16f);
    u32x4 sp = *(const u32x4*)(qk + nbase + 96);
    u32x4 res;
    #pragma unroll
    for (int i = 0; i < 4; ++i) {
        float h0 = gelu_f(fmaf(o[2*i],   r, blo(sp[i])));
        float h1 = gelu_f(fmaf(o[2*i+1], r, bhi(sp[i])));
        res[i] = packbf(h0, h1);
    }
    *(u32x4*)((u32*)xc + (n << 6) + 32 + l8 * 4) = res;
}

// ---------------- host launcher ----------------
extern "C" void kernel_launch(void* const* d_in, const int* in_sizes, int n_in,
                              void* d_out, int out_size, void* d_ws, size_t ws_size,
                              hipStream_t stream) {
    const float* x   = (const float*)d_in[0];
    const float* cW1 = (const float*)d_in[1];
    const float* cb1 = (const float*)d_in[2];
    const float* cW2 = (const float*)d_in[3];
    const float* cb2 = (const float*)d_in[4];
    const float* q1W = (const float*)d_in[5];
    const float* q1b = (const float*)d_in[6];
    const float* k1W = (const float*)d_in[7];
    const float* k1b = (const float*)d_in[8];
    const float* v1W = (const float*)d_in[9];
    const float* v1b = (const float*)d_in[10];
    const float* s1W = (const float*)d_in[11];
    const float* s1b = (const float*)d_in[12];
    const float* q2W = (const float*)d_in[13];
    const float* q2b = (const float*)d_in[14];
    const float* k2W = (const float*)d_in[15];
    const float* k2b = (const float*)d_in[16];
    const float* v2W = (const float*)d_in[17];
    const float* v2b = (const float*)d_in[18];
    const float* s2W = (const float*)d_in[19];
    const float* s2b = (const float*)d_in[20];
    const float* fW1 = (const float*)d_in[21];
    const float* fb1 = (const float*)d_in[22];
    const float* fW2 = (const float*)d_in[23];
    const float* fb2 = (const float*)d_in[24];

    char* ws = (char*)d_ws;
    float* sig  = (float*)(ws + SIG);
    float* b1   = (float*)(ws + B1OFF);
    float* b2   = (float*)(ws + B2OFF);
    u16* wc1    = (u16*)(ws + WC1);
    u16* wc2    = (u16*)(ws + WC2);
    u16* wf1    = (u16*)(ws + WF1);
    u16* wf2    = (u16*)(ws + WF2);
    u16* wp1    = (u16*)(ws + WP1);
    u16* wp2    = (u16*)(ws + WP2);
    u16* xb     = (u16*)(ws + XB);
    u16* hbuf   = (u16*)(ws + HBUF);
    u16* qkvs2  = (u16*)(ws + QKVS2);
    u16* xc     = (u16*)(ws + XC);
    u16* qkvs1  = (u16*)(ws + QKVS1);
    u16* y1     = (u16*)(ws + Y1);
    u16* tbuf   = (u16*)(ws + TBUF);
    float* gram = (float*)(ws + GRAM);
    float* out  = (float*)d_out;

    gram_kernel<<<160, 256, 0, stream>>>(cW1, cW2, fW1, fW2, gram);
    power_kernel<<<4, 256, 0, stream>>>(gram, sig);
    prep_conv_w<<<dim3(576, 4), 256, 0, stream>>>(cW1, cW2, fW1, fW2, sig,
                                                  wc1, wc2, wf1, wf2);
    prep_proj<<<260, 256, 0, stream>>>(q1W, k1W, v1W, s1W, q2W, k2W, v2W, s2W,
                                       q1b, k1b, v1b, s1b, q2b, k2b, v2b, s2b,
                                       wp1, wp2, b1, b2);
    convert_x<<<1024, 256, 0, stream>>>(x, xb);

    // proj1: [N][64] x [512][64]^T -> qkvs1 [N][512]
    mm_kernel<1, 64, 128, 0><<<dim3(512, 4), 256, 0, stream>>>(
        xb, wp1, b1, qkvs1, 512, 0, 0);
    attn1_kernel<<<NPIX / 16, 256, 0, stream>>>(qkvs1, hbuf);
    // proj2: [N][128] x [256][128]^T -> qkvs2 [N][256]
    mm_kernel<1, 128, 128, 0><<<dim3(512, 2), 256, 0, stream>>>(
        hbuf, wp2, b2, qkvs2, 256, 0, 0);
    attn2_kernel<<<NPIX / 32, 256, 0, stream>>>(qkvs2, xc);

    // conv1: im2col(xb, C=64) x [128][576]^T -> y1 [N][128], gelu
    mm_kernel<9, 64, 128, 0><<<dim3(512, 1), 256, 0, stream>>>(
        xb, wc1, cb1, y1, 128, 0, 1);
    // conv2: im2col(y1, C=128) x [64][1152]^T -> xc cols 0..63, gelu
    mm_kernel<9, 128, 64, 0><<<dim3(512, 1), 256, 0, stream>>>(
        y1, wc2, cb2, xc, 128, 0, 1);
    // conv3: im2col(xc, C=128) x [128][1152]^T -> t [N][128], gelu
    mm_kernel<9, 128, 128, 0><<<dim3(512, 1), 256, 0, stream>>>(
        xc, wf1, fb1, tbuf, 128, 0, 1);
    // conv4: im2col(t, C=128) x [64][1152]^T -> out f32 NCHW, gelu
    mm_kernel<9, 128, 64, 1><<<dim3(512, 1), 256, 0, stream>>>(
        tbuf, wf2, fb2, out, 0, 0, 1);
}

// Round 6
// 236.294 us; speedup vs baseline: 1.0154x; 1.0154x over previous
//
#include <hip/hip_runtime.h>
#include <hip/hip_bf16.h>

typedef unsigned int  u32;
typedef unsigned short u16;
typedef __attribute__((ext_vector_type(8))) short bf16x8;
typedef __attribute__((ext_vector_type(4))) float f32x4;
typedef __attribute__((ext_vector_type(4))) u32 u32x4;

#define NPIX 65536

// ---------------- ws byte offsets ----------------
constexpr size_t SIG   = 0;                   // 4 floats
constexpr size_t B1OFF = 256;                 // 512 f32
constexpr size_t B2OFF = B1OFF + 2048;        // 256 f32
constexpr size_t WC1   = B2OFF + 1024;        // 128x576 bf16
constexpr size_t WC2   = WC1 + 147456;        // 64x1152
constexpr size_t WF1   = WC2 + 147456;        // 128x1152
constexpr size_t WF2   = WF1 + 294912;        // 64x1152
constexpr size_t WP1   = WF2 + 147456;        // 512x64
constexpr size_t WP2   = WP1 + 65536;         // 256x128
constexpr size_t XB    = WP2 + 65536;         // 65536x64 bf16 (8 MB)
constexpr size_t HBUF  = XB + 8388608;        // 65536x128 bf16 (16 MB)
constexpr size_t QKVS2 = HBUF + 16777216;     // 65536x256 bf16 (32 MB)
constexpr size_t XC    = QKVS2 + 33554432;    // 65536x128 bf16 (16 MB) concat buf
constexpr size_t QKVS1 = XC + 16777216;       // 65536x512 bf16 (64 MB)
constexpr size_t Y1    = QKVS1;               // alias: y1 lives after qkvs1 dead
constexpr size_t TBUF  = QKVS1 + 16777216;    // alias: t
constexpr size_t GRAM  = QKVS1 + 67108864;    // 4 x 128x128 f32 (256 KB)

// ---------------- helpers ----------------
__device__ __forceinline__ float gelu_f(float v) {
    // exact-erf gelu, A&S 7.1.26 minimax (|erf err| <= 1.5e-7), branchless
    float xa = fabsf(v) * 0.70710678118654752f;
    float t  = __fdividef(1.0f, fmaf(0.3275911f, xa, 1.0f));
    float poly = t * fmaf(t, fmaf(t, fmaf(t, fmaf(t, 1.061405429f, -1.453152027f),
                   1.421413741f), -0.284496736f), 0.254829592f);
    float erfv = 1.0f - poly * __expf(-xa * xa);
    erfv = copysignf(erfv, v);
    return 0.5f * v * (1.0f + erfv);
}
__device__ __forceinline__ u16 f2bf(float f) {
    __hip_bfloat16 b = __float2bfloat16(f);
    return *reinterpret_cast<u16*>(&b);
}
__device__ __forceinline__ float blo(u32 u) {
    union { u32 i; float f; } x; x.i = u << 16; return x.f;
}
__device__ __forceinline__ float bhi(u32 u) {
    union { u32 i; float f; } x; x.i = u & 0xffff0000u; return x.f;
}
__device__ __forceinline__ u32 packbf(float a, float b) {
    return (u32)f2bf(a) | ((u32)f2bf(b) << 16);
}
__device__ __forceinline__ void g2l16(const void* g, void* l) {
    __builtin_amdgcn_global_load_lds(
        (const __attribute__((address_space(1))) u32*)g,
        (__attribute__((address_space(3))) u32*)l, 16, 0, 0);
}
template<int N>
__device__ __forceinline__ void waitvm() {
    asm volatile("s_waitcnt vmcnt(%0)" :: "n"(N) : "memory");
}

// ---------------- block reduction ----------------
__device__ float block_sum(float vv, float* red) {
    #pragma unroll
    for (int m = 1; m < 64; m <<= 1) vv += __shfl_xor(vv, m);
    int tid = threadIdx.x;
    __syncthreads();
    if ((tid & 63) == 0) red[tid >> 6] = vv;
    __syncthreads();
    return red[0] + red[1] + red[2] + red[3];
}

// ---------------- Gram matrix: G_w = W_w * W_w^T (tiled, parallel) ----------------
__global__ __launch_bounds__(256)
void gram_kernel(const float* __restrict__ cW1, const float* __restrict__ cW2,
                 const float* __restrict__ fW1, const float* __restrict__ fW2,
                 float* __restrict__ Gall) {
    int bid = blockIdx.x;
    const float* W; int O, K, wsel, tile;
    if (bid < 64)       { W = cW1; O = 128; K = 576;  wsel = 0; tile = bid; }
    else if (bid < 80)  { W = cW2; O = 64;  K = 1152; wsel = 1; tile = bid - 64; }
    else if (bid < 144) { W = fW1; O = 128; K = 1152; wsel = 2; tile = bid - 80; }
    else                { W = fW2; O = 64;  K = 1152; wsel = 3; tile = bid - 144; }
    int ntiles = O >> 4;
    int ti0 = (tile / ntiles) << 4, tj0 = (tile % ntiles) << 4;
    __shared__ float Wi[16][33], Wj[16][33];
    int tid = threadIdx.x;
    int ti = tid >> 4, tj = tid & 15;
    int r = tid >> 5, c = tid & 31;
    float acc = 0.f;
    for (int k0 = 0; k0 < K; k0 += 32) {
        Wi[r][c]     = W[(size_t)(ti0 + r) * K + k0 + c];
        Wi[r + 8][c] = W[(size_t)(ti0 + r + 8) * K + k0 + c];
        Wj[r][c]     = W[(size_t)(tj0 + r) * K + k0 + c];
        Wj[r + 8][c] = W[(size_t)(tj0 + r + 8) * K + k0 + c];
        __syncthreads();
        #pragma unroll
        for (int k = 0; k < 32; ++k)
            acc += Wi[ti][k] * Wj[tj][k];
        __syncthreads();
    }
    Gall[wsel * 16384 + (ti0 + ti) * 128 + (tj0 + tj)] = acc;
}

// ---------------- power iteration on G (4 blocks) ----------------
__global__ __launch_bounds__(256)
void power_kernel(const float* __restrict__ Gall, float* __restrict__ sig) {
    int wsel = blockIdx.x;
    const float* G = Gall + wsel * 16384;
    const int O = (wsel == 0 || wsel == 2) ? 128 : 64;
    __shared__ float u[128], t[128], red[4];
    int tid = threadIdx.x;
    if (tid < O) u[tid] = 1.0f / sqrtf((float)O);
    __syncthreads();
    for (int it = 0; it < 3; ++it) {
        if (tid < O) {
            float s = 0.f;
            const float4* gr = reinterpret_cast<const float4*>(G + (size_t)tid * 128);
            for (int j = 0; j < O / 4; ++j) {
                float4 g = gr[j];
                s += g.x * u[4*j] + g.y * u[4*j+1] + g.z * u[4*j+2] + g.w * u[4*j+3];
            }
            t[tid] = s;
        }
        __syncthreads();
        float loc = (tid < O) ? t[tid] * t[tid] : 0.f;
        float nt = sqrtf(block_sum(loc, red));
        if (it == 2) {
            float locd = (tid < O) ? u[tid] * t[tid] : 0.f;
            float dot = block_sum(locd, red);
            if (tid == 0) sig[wsel] = nt / sqrtf(dot + 1e-24f);
        } else {
            if (tid < O) u[tid] = t[tid] / (nt + 1e-12f);
            __syncthreads();
        }
    }
}

// ---------------- conv weight prep ----------------
__global__ __launch_bounds__(256)
void prep_conv_w(const float* __restrict__ cW1, const float* __restrict__ cW2,
                 const float* __restrict__ fW1, const float* __restrict__ fW2,
                 const float* __restrict__ sig,
                 u16* wc1, u16* wc2, u16* wf1, u16* wf2) {
    int wsel = blockIdx.y;
    const float* src; u16* dst; int O, C;
    switch (wsel) {
        case 0:  src = cW1; dst = wc1; O = 128; C = 64;  break;
        case 1:  src = cW2; dst = wc2; O = 64;  C = 128; break;
        case 2:  src = fW1; dst = wf1; O = 128; C = 128; break;
        default: src = fW2; dst = wf2; O = 64;  C = 128; break;
    }
    int idx = blockIdx.x * 256 + threadIdx.x;
    if (idx >= O * C * 9) return;
    int o = idx / (C * 9);
    int rem = idx - o * (C * 9);
    int ci = rem / 9, tap = rem - ci * 9;
    float v = src[idx] / sig[wsel];
    dst[(size_t)o * (C * 9) + tap * C + ci] = f2bf(v);
}

// ---------------- projection weight/bias prep ----------------
__global__ __launch_bounds__(256)
void prep_proj(const float* q1W, const float* k1W, const float* v1W, const float* s1W,
               const float* q2W, const float* k2W, const float* v2W, const float* s2W,
               const float* q1b, const float* k1b, const float* v1b, const float* s1b,
               const float* q2b, const float* k2b, const float* v2b, const float* s2b,
               u16* wp1, u16* wp2, float* b1, float* b2) {
    const float* W1[4] = {q1W, k1W, v1W, s1W};
    const float* W2[4] = {q2W, k2W, v2W, s2W};
    const float* Bb1[4] = {q1b, k1b, v1b, s1b};
    const float* Bb2[4] = {q2b, k2b, v2b, s2b};
    int idx = blockIdx.x * 256 + threadIdx.x;
    if (idx < 32768) {
        int w = idx >> 13, r = idx & 8191;
        wp1[(size_t)w * 8192 + r] = f2bf(W1[w][r]);
    } else if (idx < 65536) {
        int j = idx - 32768; int w = j >> 13, r = j & 8191;
        wp2[(size_t)w * 8192 + r] = f2bf(W2[w][r]);
    } else if (idx < 66048) {
        int j = idx - 65536; int w = j >> 7; b1[j] = Bb1[w][j & 127];
    } else if (idx < 66304) {
        int j = idx - 66048; int w = j >> 6; b2[j] = Bb2[w][j & 63];
    }
}

// ---------------- x NCHW f32 -> [pix][64] bf16 ----------------
__global__ __launch_bounds__(256)
void convert_x(const float* __restrict__ x, u16* __restrict__ xb) {
    __shared__ float tile[64][65];
    int b = blockIdx.x >> 6, y = blockIdx.x & 63;
    int tid = threadIdx.x;
    #pragma unroll
    for (int i = 0; i < 16; ++i) {
        int c = (tid >> 6) + i * 4;
        tile[c][tid & 63] = x[(((size_t)b * 64 + c) << 12) + (y << 6) + (tid & 63)];
    }
    __syncthreads();
    #pragma unroll
    for (int i = 0; i < 16; ++i) {
        int idx = tid + i * 256;
        int p = idx >> 6, c = idx & 63;
        xb[(((size_t)b << 12) + (y << 6) + p) * 64 + c] = f2bf(tile[c][p]);
    }
}

// ---------------- bf16 MFMA GEMM, implicit im2col ----------------
// 4-buffer ring, depth-2 prefetch, counted vmcnt (never drains to 0 mid-loop).
// LDS tiles [rows][32] bf16, 16B chunk c of row r at slot c ^ ((r>>1)&3)
// (inverse-swizzled global source + swizzled ds_read, both-sides pairing).
template<int TAPS, int CC, int BN, int OUTM>
__global__ __launch_bounds__(256)
void mm_kernel(const u16* __restrict__ A, const u16* __restrict__ Bw,
               const float* __restrict__ bias, void* __restrict__ Cout,
               int ostride, int ocol0, int do_gelu) {
    constexpr int K = CC * TAPS;
    constexpr int NSTEP = K / 32;
    constexpr int NF = BN / 32;
    constexpr int HN = BN / 2;
    constexpr int LPS = 2 + BN / 64;       // global_load_lds per thread per stage
    __shared__ u16 Als[4][128 * 32];
    __shared__ u16 Bls[4][BN * 32];
    const int tid = threadIdx.x;
    const int w = tid >> 6;
    const int lane = tid & 63;
    const int m0 = blockIdx.x * 128;
    const int nt0 = blockIdx.y * BN;
    const int wm = w >> 1, wn = w & 1;
    // staging source swizzle: LDS row (tid>>2)(+64), slot (tid&3);
    // fetch global chunk slot ^ ((row>>1)&3) = (tid&3) ^ ((tid>>3)&3)
    const int csrc = (((tid & 3) ^ ((tid >> 3) & 3)) << 3);

    // ---- hoisted per-thread staging constants ----
    const int arow = tid >> 2;
    const int mA0 = m0 + arow, mA1 = mA0 + 64;
    const int yA0 = (mA0 >> 6) & 63, xA0 = mA0 & 63, ibA0 = mA0 & ~4095;
    const int yA1 = (mA1 >> 6) & 63, xA1 = mA1 & 63, ibA1 = mA1 & ~4095;
    const u16* Brow0 = Bw + (size_t)(nt0 + arow) * K + csrc;
    const u16* Brow1 = Bw + (size_t)(nt0 + arow + (BN > 64 ? 64 : 0)) * K + csrc;

    // ---- hoisted swizzled ds_read offsets (u16 elements) ----
    int offA[4], offB[NF];
    #pragma unroll
    for (int mf = 0; mf < 4; ++mf) {
        int R = wm * 64 + mf * 16 + (lane & 15);
        int C = ((lane >> 4) ^ ((R >> 1) & 3)) << 3;
        offA[mf] = R * 32 + C;
    }
    #pragma unroll
    for (int nf = 0; nf < NF; ++nf) {
        int Rb = wn * HN + nf * 16 + (lane & 15);
        int Cb = ((lane >> 4) ^ ((Rb >> 1) & 3)) << 3;
        offB[nf] = Rb * 32 + Cb;
    }

    f32x4 acc[4][NF];
    #pragma unroll
    for (int i = 0; i < 4; ++i)
        #pragma unroll
        for (int j = 0; j < NF; ++j) {
            f32x4 z = {0.f, 0.f, 0.f, 0.f};
            acc[i][j] = z;
        }

    auto stage = [&](int s) {
        const int buf = s & 3;
        const int kk = s * 32;
        const u16 *ga0, *ga1;
        if constexpr (TAPS == 9) {
            const int tap = kk / CC;             // power-of-2 shift
            const int ci0 = kk - tap * CC;
            const int t3 = (tap * 11) >> 5;      // tap/3 for tap<9
            const int dy = t3 - 1, dx = tap - t3 * 3 - 1;
            int yy0 = min(max(yA0 + dy, 0), 63), xx0 = min(max(xA0 + dx, 0), 63);
            int yy1 = min(max(yA1 + dy, 0), 63), xx1 = min(max(xA1 + dx, 0), 63);
            ga0 = A + (size_t)(ibA0 | (yy0 << 6) | xx0) * CC + ci0 + csrc;
            ga1 = A + (size_t)(ibA1 | (yy1 << 6) | xx1) * CC + ci0 + csrc;
        } else {
            ga0 = A + (size_t)mA0 * CC + kk + csrc;
            ga1 = A + (size_t)mA1 * CC + kk + csrc;
        }
        g2l16(ga0, &Als[buf][w * 512]);
        g2l16(ga1, &Als[buf][w * 512 + 2048]);
        g2l16(Brow0 + kk, &Bls[buf][w * 512]);
        if constexpr (BN > 64)
            g2l16(Brow1 + kk, &Bls[buf][w * 512 + 2048]);
    };

    stage(0);
    stage(1);

    for (int kt = 0; kt < NSTEP; ++kt) {
        if (kt + 2 < NSTEP) stage(kt + 2);
        const int ahead = NSTEP - 1 - kt;
        if (ahead >= 2)      waitvm<2 * LPS>();   // tile kt landed; kt+1,kt+2 in flight
        else if (ahead == 1) waitvm<LPS>();
        else                 waitvm<0>();
        __builtin_amdgcn_s_barrier();
        __builtin_amdgcn_sched_barrier(0);
        const u16* Ab = &Als[kt & 3][0];
        const u16* Bb = &Bls[kt & 3][0];
        bf16x8 af[4];
        #pragma unroll
        for (int mf = 0; mf < 4; ++mf)
            af[mf] = *reinterpret_cast<const bf16x8*>(Ab + offA[mf]);
        #pragma unroll
        for (int nf = 0; nf < NF; ++nf) {
            bf16x8 bfv = *reinterpret_cast<const bf16x8*>(Bb + offB[nf]);
            #pragma unroll
            for (int mf = 0; mf < 4; ++mf)
                acc[mf][nf] = __builtin_amdgcn_mfma_f32_16x16x32_bf16(
                    af[mf], bfv, acc[mf][nf], 0, 0, 0);
        }
    }

    // epilogue
    #pragma unroll
    for (int mf = 0; mf < 4; ++mf) {
        int mrow = m0 + wm * 64 + mf * 16 + (lane >> 4) * 4;
        #pragma unroll
        for (int nf = 0; nf < NF; ++nf) {
            int col = nt0 + wn * HN + nf * 16 + (lane & 15);
            float bv = bias[col];
            if (OUTM == 0) {
                u16* Co = (u16*)Cout;
                #pragma unroll
                for (int j = 0; j < 4; ++j) {
                    float v = acc[mf][nf][j] + bv;
                    if (do_gelu) v = gelu_f(v);
                    Co[(size_t)(mrow + j) * ostride + ocol0 + col] = f2bf(v);
                }
            } else {
                float* Co = (float*)Cout;
                int b = m0 >> 12;
                int pixb = (mrow & 4095);
                f32x4 vv;
                #pragma unroll
                for (int j = 0; j < 4; ++j) {
                    float v = acc[mf][nf][j] + bv;
                    vv[j] = gelu_f(v);
                }
                *reinterpret_cast<f32x4*>(&Co[((size_t)(b * 64 + col)) * 4096 + pixb]) = vv;
            }
        }
    }
}

// ---------------- attention layer 1: heads=8, d=16, 8ch/lane ----------------
// qkvs row = 256 u32 (Q 0..63, K 64..127, V 128..191, S 192..255)
__global__ __launch_bounds__(256)
void attn1_kernel(const u16* __restrict__ qkvs, u16* __restrict__ h) {
    const int tid = threadIdx.x;
    const int l16 = tid & 15;
    const int n = blockIdx.x * 16 + (tid >> 4);
    const int y = (n >> 6) & 63, x = n & 63;
    const u32* qk = (const u32*)qkvs;
    const int nbase = (n << 8) + l16 * 4;

    u32x4 qp = *(const u32x4*)(qk + nbase);
    float q[8];
    #pragma unroll
    for (int i = 0; i < 4; ++i) { q[2*i] = blo(qp[i]); q[2*i+1] = bhi(qp[i]); }

    float al[9];
    float mx = -1e30f;
    #pragma unroll
    for (int e = 0; e < 9; ++e) {
        const int dy = e / 3 - 1, dx = e % 3 - 1;
        const bool valid = (unsigned)(y + dy) < 64u && (unsigned)(x + dx) < 64u;
        const int off = valid ? ((dy * 64 + dx) << 8) : 0;
        u32x4 kp = *(const u32x4*)(qk + nbase + off + 64);
        float p = 0.f;
        #pragma unroll
        for (int i = 0; i < 4; ++i) {
            p = fmaf(q[2*i],   blo(kp[i]), p);
            p = fmaf(q[2*i+1], bhi(kp[i]), p);
        }
        p += __shfl_xor(p, 1);       // head = 16ch = 2 lanes
        al[e] = valid ? p * 0.25f : -1e30f;
        mx = fmaxf(mx, al[e]);
    }
    float s = 0.f;
    #pragma unroll
    for (int e = 0; e < 9; ++e) { al[e] = __expf(al[e] - mx); s += al[e]; }

    float o[8] = {0.f, 0.f, 0.f, 0.f, 0.f, 0.f, 0.f, 0.f};
    #pragma unroll
    for (int e = 0; e < 9; ++e) {
        const int dy = e / 3 - 1, dx = e % 3 - 1;
        const bool valid = (unsigned)(y + dy) < 64u && (unsigned)(x + dx) < 64u;
        const int off = valid ? ((dy * 64 + dx) << 8) : 0;
        u32x4 vp = *(const u32x4*)(qk + nbase + off + 128);
        const float a = al[e];
        #pragma unroll
        for (int i = 0; i < 4; ++i) {
            o[2*i]   = fmaf(a, blo(vp[i]), o[2*i]);
            o[2*i+1] = fmaf(a, bhi(vp[i]), o[2*i+1]);
        }
    }
    const float r = __fdividef(1.0f, s + 1e-16f);
    u32x4 sp = *(const u32x4*)(qk + nbase + 192);
    u32x4 res;
    #pragma unroll
    for (int i = 0; i < 4; ++i) {
        float h0 = gelu_f(fmaf(o[2*i],   r, blo(sp[i])));
        float h1 = gelu_f(fmaf(o[2*i+1], r, bhi(sp[i])));
        res[i] = packbf(h0, h1);
    }
    *(u32x4*)((u32*)h + (n << 6) + l16 * 4) = res;
}

// ---------------- attention layer 2: heads=1, d=64, 8ch/lane ----------------
// qkvs row = 128 u32 (Q 0..31, K 32..63, V 64..95, S 96..127); out -> xc cols 64..127
__global__ __launch_bounds__(256)
void attn2_kernel(const u16* __restrict__ qkvs, u16* __restrict__ xc) {
    const int tid = threadIdx.x;
    const int l8 = tid & 7;
    const int n = blockIdx.x * 32 + (tid >> 3);
    const int y = (n >> 6) & 63, x = n & 63;
    const u32* qk = (const u32*)qkvs;
    const int nbase = (n << 7) + l8 * 4;

    u32x4 qp = *(const u32x4*)(qk + nbase);
    float q[8];
    #pragma unroll
    for (int i = 0; i < 4; ++i) { q[2*i] = blo(qp[i]); q[2*i+1] = bhi(qp[i]); }

    float al[9];
    float mx = -1e30f;
    #pragma unroll
    for (int e = 0; e < 9; ++e) {
        const int dy = e / 3 - 1, dx = e % 3 - 1;
        const bool valid = (unsigned)(y + dy) < 64u && (unsigned)(x + dx) < 64u;
        const int off = valid ? ((dy * 64 + dx) << 7) : 0;
        u32x4 kp = *(const u32x4*)(qk + nbase + off + 32);
        float p = 0.f;
        #pragma unroll
        for (int i = 0; i < 4; ++i) {
            p = fmaf(q[2*i],   blo(kp[i]), p);
            p = fmaf(q[2*i+1], bhi(kp[i]), p);
        }
        p += __shfl_xor(p, 1);
        p += __shfl_xor(p, 2);
        p += __shfl_xor(p, 4);       // head = 64ch = 8 lanes
        al[e] = valid ? p * 0.125f : -1e30f;
        mx = fmaxf(mx, al[e]);
    }
    float s = 0.f;
    #pragma unroll
    for (int e = 0; e < 9; ++e) { al[e] = __expf(al[e] - mx); s += al[e]; }

    float o[8] = {0.f, 0.f, 0.f, 0.f, 0.f, 0.f, 0.f, 0.f};
    #pragma unroll
    for (int e = 0; e < 9; ++e) {
        const int dy = e / 3 - 1, dx = e % 3 - 1;
        const bool valid = (unsigned)(y + dy) < 64u && (unsigned)(x + dx) < 64u;
        const int off = valid ? ((dy * 64 + dx) << 7) : 0;
        u32x4 vp = *(const u32x4*)(qk + nbase + off + 64);
        const float a = al[e];
        #pragma unroll
        for (int i = 0; i < 4; ++i) {
            o[2*i]   = fmaf(a, blo(vp[i]), o[2*i]);
            o[2*i+1] = fmaf(a, bhi(vp[i]), o[2*i+1]);
        }
    }
    const float r = __fdividef(1.0f, s + 1e-16f);
    u32x4 sp = *(const u32x4*)(qk + nbase + 96);
    u32x4 res;
    #pragma unroll
    for (int i = 0; i < 4; ++i) {
        float h0 = gelu_f(fmaf(o[2*i],   r, blo(sp[i])));
        float h1 = gelu_f(fmaf(o[2*i+1], r, bhi(sp[i])));
        res[i] = packbf(h0, h1);
    }
    *(u32x4*)((u32*)xc + (n << 6) + 32 + l8 * 4) = res;
}

// ---------------- host launcher ----------------
extern "C" void kernel_launch(void* const* d_in, const int* in_sizes, int n_in,
                              void* d_out, int out_size, void* d_ws, size_t ws_size,
                              hipStream_t stream) {
    const float* x   = (const float*)d_in[0];
    const float* cW1 = (const float*)d_in[1];
    const float* cb1 = (const float*)d_in[2];
    const float* cW2 = (const float*)d_in[3];
    const float* cb2 = (const float*)d_in[4];
    const float* q1W = (const float*)d_in[5];
    const float* q1b = (const float*)d_in[6];
    const float* k1W = (const float*)d_in[7];
    const float* k1b = (const float*)d_in[8];
    const float* v1W = (const float*)d_in[9];
    const float* v1b = (const float*)d_in[10];
    const float* s1W = (const float*)d_in[11];
    const float* s1b = (const float*)d_in[12];
    const float* q2W = (const float*)d_in[13];
    const float* q2b = (const float*)d_in[14];
    const float* k2W = (const float*)d_in[15];
    const float* k2b = (const float*)d_in[16];
    const float* v2W = (const float*)d_in[17];
    const float* v2b = (const float*)d_in[18];
    const float* s2W = (const float*)d_in[19];
    const float* s2b = (const float*)d_in[20];
    const float* fW1 = (const float*)d_in[21];
    const float* fb1 = (const float*)d_in[22];
    const float* fW2 = (const float*)d_in[23];
    const float* fb2 = (const float*)d_in[24];

    char* ws = (char*)d_ws;
    float* sig  = (float*)(ws + SIG);
    float* b1   = (float*)(ws + B1OFF);
    float* b2   = (float*)(ws + B2OFF);
    u16* wc1    = (u16*)(ws + WC1);
    u16* wc2    = (u16*)(ws + WC2);
    u16* wf1    = (u16*)(ws + WF1);
    u16* wf2    = (u16*)(ws + WF2);
    u16* wp1    = (u16*)(ws + WP1);
    u16* wp2    = (u16*)(ws + WP2);
    u16* xb     = (u16*)(ws + XB);
    u16* hbuf   = (u16*)(ws + HBUF);
    u16* qkvs2  = (u16*)(ws + QKVS2);
    u16* xc     = (u16*)(ws + XC);
    u16* qkvs1  = (u16*)(ws + QKVS1);
    u16* y1     = (u16*)(ws + Y1);
    u16* tbuf   = (u16*)(ws + TBUF);
    float* gram = (float*)(ws + GRAM);
    float* out  = (float*)d_out;

    gram_kernel<<<160, 256, 0, stream>>>(cW1, cW2, fW1, fW2, gram);
    power_kernel<<<4, 256, 0, stream>>>(gram, sig);
    prep_conv_w<<<dim3(576, 4), 256, 0, stream>>>(cW1, cW2, fW1, fW2, sig,
                                                  wc1, wc2, wf1, wf2);
    prep_proj<<<260, 256, 0, stream>>>(q1W, k1W, v1W, s1W, q2W, k2W, v2W, s2W,
                                       q1b, k1b, v1b, s1b, q2b, k2b, v2b, s2b,
                                       wp1, wp2, b1, b2);
    convert_x<<<1024, 256, 0, stream>>>(x, xb);

    // proj1: [N][64] x [512][64]^T -> qkvs1 [N][512]
    mm_kernel<1, 64, 128, 0><<<dim3(512, 4), 256, 0, stream>>>(
        xb, wp1, b1, qkvs1, 512, 0, 0);
    attn1_kernel<<<NPIX / 16, 256, 0, stream>>>(qkvs1, hbuf);
    // proj2: [N][128] x [256][128]^T -> qkvs2 [N][256]
    mm_kernel<1, 128, 128, 0><<<dim3(512, 2), 256, 0, stream>>>(
        hbuf, wp2, b2, qkvs2, 256, 0, 0);
    attn2_kernel<<<NPIX / 32, 256, 0, stream>>>(qkvs2, xc);

    // conv1: im2col(xb, C=64) x [128][576]^T -> y1 [N][128], gelu
    mm_kernel<9, 64, 128, 0><<<dim3(512, 1), 256, 0, stream>>>(
        xb, wc1, cb1, y1, 128, 0, 1);
    // conv2: im2col(y1, C=128) x [64][1152]^T -> xc cols 0..63, gelu
    mm_kernel<9, 128, 64, 0><<<dim3(512, 1), 256, 0, stream>>>(
        y1, wc2, cb2, xc, 128, 0, 1);
    // conv3: im2col(xc, C=128) x [128][1152]^T -> t [N][128], gelu
    mm_kernel<9, 128, 128, 0><<<dim3(512, 1), 256, 0, stream>>>(
        xc, wf1, fb1, tbuf, 128, 0, 1);
    // conv4: im2col(t, C=128) x [64][1152]^T -> out f32 NCHW, gelu
    mm_kernel<9, 128, 64, 1><<<dim3(512, 1), 256, 0, stream>>>(
        tbuf, wf2, fb2, out, 0, 0, 1);
}

// Round 7
// 232.244 us; speedup vs baseline: 1.0331x; 1.0174x over previous
//
#include <hip/hip_runtime.h>
#include <hip/hip_bf16.h>

typedef unsigned int  u32;
typedef unsigned short u16;
typedef __attribute__((ext_vector_type(8))) short bf16x8;
typedef __attribute__((ext_vector_type(4))) float f32x4;
typedef __attribute__((ext_vector_type(4))) u32 u32x4;

#define NPIX 65536

// ---------------- ws byte offsets ----------------
constexpr size_t SIG   = 0;                   // 4 floats
constexpr size_t B1OFF = 256;                 // 512 f32
constexpr size_t B2OFF = B1OFF + 2048;        // 256 f32
constexpr size_t WC1   = B2OFF + 1024;        // 128x576 bf16
constexpr size_t WC2   = WC1 + 147456;        // 64x1152
constexpr size_t WF1   = WC2 + 147456;        // 128x1152
constexpr size_t WF2   = WF1 + 294912;        // 64x1152
constexpr size_t WP1   = WF2 + 147456;        // 512x64
constexpr size_t WP2   = WP1 + 65536;         // 256x128
constexpr size_t XB    = WP2 + 65536;         // 65536x64 bf16 (8 MB)
constexpr size_t HBUF  = XB + 8388608;        // 65536x128 bf16 (16 MB)
constexpr size_t QKVS2 = HBUF + 16777216;     // 65536x256 bf16 (32 MB)
constexpr size_t XC    = QKVS2 + 33554432;    // 65536x128 bf16 (16 MB) concat buf
constexpr size_t QKVS1 = XC + 16777216;       // 65536x512 bf16 (64 MB)
constexpr size_t Y1    = QKVS1;               // alias: y1 lives after qkvs1 dead
constexpr size_t TBUF  = QKVS1 + 16777216;    // alias: t
constexpr size_t GRAM  = QKVS1 + 67108864;    // 4 x 128x128 f32 (256 KB)

// ---------------- helpers ----------------
__device__ __forceinline__ float gelu_f(float v) {
    // exact-erf gelu, A&S 7.1.26 minimax (|erf err| <= 1.5e-7), branchless
    float xa = fabsf(v) * 0.70710678118654752f;
    float t  = __fdividef(1.0f, fmaf(0.3275911f, xa, 1.0f));
    float poly = t * fmaf(t, fmaf(t, fmaf(t, fmaf(t, 1.061405429f, -1.453152027f),
                   1.421413741f), -0.284496736f), 0.254829592f);
    float erfv = 1.0f - poly * __expf(-xa * xa);
    erfv = copysignf(erfv, v);
    return 0.5f * v * (1.0f + erfv);
}
__device__ __forceinline__ u16 f2bf(float f) {
    __hip_bfloat16 b = __float2bfloat16(f);
    return *reinterpret_cast<u16*>(&b);
}
__device__ __forceinline__ float blo(u32 u) {
    union { u32 i; float f; } x; x.i = u << 16; return x.f;
}
__device__ __forceinline__ float bhi(u32 u) {
    union { u32 i; float f; } x; x.i = u & 0xffff0000u; return x.f;
}
__device__ __forceinline__ u32 packbf(float a, float b) {
    return (u32)f2bf(a) | ((u32)f2bf(b) << 16);
}
__device__ __forceinline__ void g2l16(const void* g, void* l) {
    __builtin_amdgcn_global_load_lds(
        (const __attribute__((address_space(1))) u32*)g,
        (__attribute__((address_space(3))) u32*)l, 16, 0, 0);
}
template<int N>
__device__ __forceinline__ void waitvm() {
    asm volatile("s_waitcnt vmcnt(%0)" :: "n"(N) : "memory");
}

// ---------------- block reduction ----------------
__device__ float block_sum(float vv, float* red) {
    #pragma unroll
    for (int m = 1; m < 64; m <<= 1) vv += __shfl_xor(vv, m);
    int tid = threadIdx.x;
    __syncthreads();
    if ((tid & 63) == 0) red[tid >> 6] = vv;
    __syncthreads();
    return red[0] + red[1] + red[2] + red[3];
}

// ---------------- Gram matrix: G_w = W_w * W_w^T (tiled, parallel) ----------------
__global__ __launch_bounds__(256)
void gram_kernel(const float* __restrict__ cW1, const float* __restrict__ cW2,
                 const float* __restrict__ fW1, const float* __restrict__ fW2,
                 float* __restrict__ Gall) {
    int bid = blockIdx.x;
    const float* W; int O, K, wsel, tile;
    if (bid < 64)       { W = cW1; O = 128; K = 576;  wsel = 0; tile = bid; }
    else if (bid < 80)  { W = cW2; O = 64;  K = 1152; wsel = 1; tile = bid - 64; }
    else if (bid < 144) { W = fW1; O = 128; K = 1152; wsel = 2; tile = bid - 80; }
    else                { W = fW2; O = 64;  K = 1152; wsel = 3; tile = bid - 144; }
    int ntiles = O >> 4;
    int ti0 = (tile / ntiles) << 4, tj0 = (tile % ntiles) << 4;
    __shared__ float Wi[16][33], Wj[16][33];
    int tid = threadIdx.x;
    int ti = tid >> 4, tj = tid & 15;
    int r = tid >> 5, c = tid & 31;
    float acc = 0.f;
    for (int k0 = 0; k0 < K; k0 += 32) {
        Wi[r][c]     = W[(size_t)(ti0 + r) * K + k0 + c];
        Wi[r + 8][c] = W[(size_t)(ti0 + r + 8) * K + k0 + c];
        Wj[r][c]     = W[(size_t)(tj0 + r) * K + k0 + c];
        Wj[r + 8][c] = W[(size_t)(tj0 + r + 8) * K + k0 + c];
        __syncthreads();
        #pragma unroll
        for (int k = 0; k < 32; ++k)
            acc += Wi[ti][k] * Wj[tj][k];
        __syncthreads();
    }
    Gall[wsel * 16384 + (ti0 + ti) * 128 + (tj0 + tj)] = acc;
}

// ---------------- power iteration on G (4 blocks) ----------------
__global__ __launch_bounds__(256)
void power_kernel(const float* __restrict__ Gall, float* __restrict__ sig) {
    int wsel = blockIdx.x;
    const float* G = Gall + wsel * 16384;
    const int O = (wsel == 0 || wsel == 2) ? 128 : 64;
    __shared__ float u[128], t[128], red[4];
    int tid = threadIdx.x;
    if (tid < O) u[tid] = 1.0f / sqrtf((float)O);
    __syncthreads();
    for (int it = 0; it < 3; ++it) {
        if (tid < O) {
            float s = 0.f;
            const float4* gr = reinterpret_cast<const float4*>(G + (size_t)tid * 128);
            for (int j = 0; j < O / 4; ++j) {
                float4 g = gr[j];
                s += g.x * u[4*j] + g.y * u[4*j+1] + g.z * u[4*j+2] + g.w * u[4*j+3];
            }
            t[tid] = s;
        }
        __syncthreads();
        float loc = (tid < O) ? t[tid] * t[tid] : 0.f;
        float nt = sqrtf(block_sum(loc, red));
        if (it == 2) {
            float locd = (tid < O) ? u[tid] * t[tid] : 0.f;
            float dot = block_sum(locd, red);
            if (tid == 0) sig[wsel] = nt / sqrtf(dot + 1e-24f);
        } else {
            if (tid < O) u[tid] = t[tid] / (nt + 1e-12f);
            __syncthreads();
        }
    }
}

// ---------------- conv weight prep ----------------
__global__ __launch_bounds__(256)
void prep_conv_w(const float* __restrict__ cW1, const float* __restrict__ cW2,
                 const float* __restrict__ fW1, const float* __restrict__ fW2,
                 const float* __restrict__ sig,
                 u16* wc1, u16* wc2, u16* wf1, u16* wf2) {
    int wsel = blockIdx.y;
    const float* src; u16* dst; int O, C;
    switch (wsel) {
        case 0:  src = cW1; dst = wc1; O = 128; C = 64;  break;
        case 1:  src = cW2; dst = wc2; O = 64;  C = 128; break;
        case 2:  src = fW1; dst = wf1; O = 128; C = 128; break;
        default: src = fW2; dst = wf2; O = 64;  C = 128; break;
    }
    int idx = blockIdx.x * 256 + threadIdx.x;
    if (idx >= O * C * 9) return;
    int o = idx / (C * 9);
    int rem = idx - o * (C * 9);
    int ci = rem / 9, tap = rem - ci * 9;
    float v = src[idx] / sig[wsel];
    dst[(size_t)o * (C * 9) + tap * C + ci] = f2bf(v);
}

// ---------------- projection weight/bias prep ----------------
__global__ __launch_bounds__(256)
void prep_proj(const float* q1W, const float* k1W, const float* v1W, const float* s1W,
               const float* q2W, const float* k2W, const float* v2W, const float* s2W,
               const float* q1b, const float* k1b, const float* v1b, const float* s1b,
               const float* q2b, const float* k2b, const float* v2b, const float* s2b,
               u16* wp1, u16* wp2, float* b1, float* b2) {
    const float* W1[4] = {q1W, k1W, v1W, s1W};
    const float* W2[4] = {q2W, k2W, v2W, s2W};
    const float* Bb1[4] = {q1b, k1b, v1b, s1b};
    const float* Bb2[4] = {q2b, k2b, v2b, s2b};
    int idx = blockIdx.x * 256 + threadIdx.x;
    if (idx < 32768) {
        int w = idx >> 13, r = idx & 8191;
        wp1[(size_t)w * 8192 + r] = f2bf(W1[w][r]);
    } else if (idx < 65536) {
        int j = idx - 32768; int w = j >> 13, r = j & 8191;
        wp2[(size_t)w * 8192 + r] = f2bf(W2[w][r]);
    } else if (idx < 66048) {
        int j = idx - 65536; int w = j >> 7; b1[j] = Bb1[w][j & 127];
    } else if (idx < 66304) {
        int j = idx - 66048; int w = j >> 6; b2[j] = Bb2[w][j & 63];
    }
}

// ---------------- x NCHW f32 -> [pix][64] bf16 ----------------
__global__ __launch_bounds__(256)
void convert_x(const float* __restrict__ x, u16* __restrict__ xb) {
    __shared__ float tile[64][65];
    int b = blockIdx.x >> 6, y = blockIdx.x & 63;
    int tid = threadIdx.x;
    #pragma unroll
    for (int i = 0; i < 16; ++i) {
        int c = (tid >> 6) + i * 4;
        tile[c][tid & 63] = x[(((size_t)b * 64 + c) << 12) + (y << 6) + (tid & 63)];
    }
    __syncthreads();
    #pragma unroll
    for (int i = 0; i < 16; ++i) {
        int idx = tid + i * 256;
        int p = idx >> 6, c = idx & 63;
        xb[(((size_t)b << 12) + (y << 6) + p) * 64 + c] = f2bf(tile[c][p]);
    }
}

// ---------------- bf16 MFMA GEMM, implicit im2col ----------------
// BM=64, 4 waves x (32x BN/2) each -> grid 1024 M-blocks = 4 blocks/CU,
// 16 waves/CU (latency-bound fix). Ring-3 LDS, stage AFTER barrier
// (post-barrier staging into (kt+2)%3 = (kt-1)%3 is safe: all waves have
// finished step kt-1 reads). Counted vmcnt(LPS), never 0 mid-loop.
// LDS [row][32] bf16, 16B chunk c of row r at slot c ^ ((r>>1)&3).
template<int TAPS, int CC, int BN, int OUTM>
__global__ __launch_bounds__(256)
void mm_kernel(const u16* __restrict__ A, const u16* __restrict__ Bw,
               const float* __restrict__ bias, void* __restrict__ Cout,
               int ostride, int ocol0, int do_gelu) {
    constexpr int K = CC * TAPS;
    constexpr int NSTEP = K / 32;
    constexpr int NF = BN / 32;            // B frags per wave (wave covers BN/2 cols)
    constexpr int HN = BN / 2;
    constexpr int LPS = 1 + BN / 64;       // global_load_lds per thread per stage
    __shared__ u16 Als[3][64 * 32];
    __shared__ u16 Bls[3][BN * 32];
    const int tid = threadIdx.x;
    const int w = tid >> 6;
    const int lane = tid & 63;
    const int m0 = blockIdx.x * 64;
    const int nt0 = blockIdx.y * BN;
    const int wm = w >> 1, wn = w & 1;
    // staging: LDS row tid>>2, slot tid&3; fetch global chunk slot^((row>>1)&3)
    const int csrc = (((tid & 3) ^ ((tid >> 3) & 3)) << 3);

    // hoisted per-thread staging constants
    const int arow = tid >> 2;
    const int mA = m0 + arow;
    const int yA = (mA >> 6) & 63, xA = mA & 63, ibA = mA & ~4095;
    const u16* Brow0 = Bw + (size_t)(nt0 + arow) * K + csrc;
    const u16* Brow1 = Bw + (size_t)(nt0 + arow + (BN > 64 ? 64 : 0)) * K + csrc;

    // hoisted swizzled ds_read offsets (u16 elements)
    int offA[2], offB[NF];
    #pragma unroll
    for (int mf = 0; mf < 2; ++mf) {
        int R = wm * 32 + mf * 16 + (lane & 15);
        int C = ((lane >> 4) ^ ((R >> 1) & 3)) << 3;
        offA[mf] = R * 32 + C;
    }
    #pragma unroll
    for (int nf = 0; nf < NF; ++nf) {
        int Rb = wn * HN + nf * 16 + (lane & 15);
        int Cb = ((lane >> 4) ^ ((Rb >> 1) & 3)) << 3;
        offB[nf] = Rb * 32 + Cb;
    }

    f32x4 acc[2][NF];
    #pragma unroll
    for (int i = 0; i < 2; ++i)
        #pragma unroll
        for (int j = 0; j < NF; ++j) {
            f32x4 z = {0.f, 0.f, 0.f, 0.f};
            acc[i][j] = z;
        }

    auto stage = [&](int s) {
        const int buf = s % 3;
        const int kk = s * 32;
        const u16* ga;
        if constexpr (TAPS == 9) {
            const int tap = kk / CC;             // power-of-2 shift
            const int ci0 = kk - tap * CC;
            const int t3 = (tap * 11) >> 5;      // tap/3 for tap<9
            const int dy = t3 - 1, dx = tap - t3 * 3 - 1;
            int yy = min(max(yA + dy, 0), 63), xx = min(max(xA + dx, 0), 63);
            ga = A + (size_t)(ibA | (yy << 6) | xx) * CC + ci0 + csrc;
        } else {
            ga = A + (size_t)mA * CC + kk + csrc;
        }
        g2l16(ga, &Als[buf][w * 512]);
        g2l16(Brow0 + kk, &Bls[buf][w * 512]);
        if constexpr (BN > 64)
            g2l16(Brow1 + kk, &Bls[buf][w * 512 + 2048]);
    };

    stage(0);
    stage(1);

    for (int kt = 0; kt < NSTEP; ++kt) {
        // own tile-kt loads landed:
        if (kt < NSTEP - 1) waitvm<LPS>(); else waitvm<0>();
        __builtin_amdgcn_s_barrier();          // everyone's tile-kt loads landed
        __builtin_amdgcn_sched_barrier(0);
        if (kt + 2 < NSTEP) stage(kt + 2);     // safe: all finished kt-1 reads
        __builtin_amdgcn_sched_barrier(0);
        const u16* Ab = &Als[kt % 3][0];
        const u16* Bb = &Bls[kt % 3][0];
        bf16x8 af[2];
        #pragma unroll
        for (int mf = 0; mf < 2; ++mf)
            af[mf] = *reinterpret_cast<const bf16x8*>(Ab + offA[mf]);
        #pragma unroll
        for (int nf = 0; nf < NF; ++nf) {
            bf16x8 bfv = *reinterpret_cast<const bf16x8*>(Bb + offB[nf]);
            #pragma unroll
            for (int mf = 0; mf < 2; ++mf)
                acc[mf][nf] = __builtin_amdgcn_mfma_f32_16x16x32_bf16(
                    af[mf], bfv, acc[mf][nf], 0, 0, 0);
        }
    }

    // epilogue
    #pragma unroll
    for (int mf = 0; mf < 2; ++mf) {
        int mrow = m0 + wm * 32 + mf * 16 + (lane >> 4) * 4;
        #pragma unroll
        for (int nf = 0; nf < NF; ++nf) {
            int col = nt0 + wn * HN + nf * 16 + (lane & 15);
            float bv = bias[col];
            if (OUTM == 0) {
                u16* Co = (u16*)Cout;
                #pragma unroll
                for (int j = 0; j < 4; ++j) {
                    float v = acc[mf][nf][j] + bv;
                    if (do_gelu) v = gelu_f(v);
                    Co[(size_t)(mrow + j) * ostride + ocol0 + col] = f2bf(v);
                }
            } else {
                float* Co = (float*)Cout;
                int b = m0 >> 12;
                int pixb = (mrow & 4095);
                f32x4 vv;
                #pragma unroll
                for (int j = 0; j < 4; ++j) {
                    float v = acc[mf][nf][j] + bv;
                    vv[j] = gelu_f(v);
                }
                *reinterpret_cast<f32x4*>(&Co[((size_t)(b * 64 + col)) * 4096 + pixb]) = vv;
            }
        }
    }
}

// ---------------- attention layer 1: heads=8, d=16, 8ch/lane ----------------
// qkvs row = 256 u32 (Q 0..63, K 64..127, V 128..191, S 192..255)
__global__ __launch_bounds__(256)
void attn1_kernel(const u16* __restrict__ qkvs, u16* __restrict__ h) {
    const int tid = threadIdx.x;
    const int l16 = tid & 15;
    const int n = blockIdx.x * 16 + (tid >> 4);
    const int y = (n >> 6) & 63, x = n & 63;
    const u32* qk = (const u32*)qkvs;
    const int nbase = (n << 8) + l16 * 4;

    u32x4 qp = *(const u32x4*)(qk + nbase);
    float q[8];
    #pragma unroll
    for (int i = 0; i < 4; ++i) { q[2*i] = blo(qp[i]); q[2*i+1] = bhi(qp[i]); }

    float al[9];
    float mx = -1e30f;
    #pragma unroll
    for (int e = 0; e < 9; ++e) {
        const int dy = e / 3 - 1, dx = e % 3 - 1;
        const bool valid = (unsigned)(y + dy) < 64u && (unsigned)(x + dx) < 64u;
        const int off = valid ? ((dy * 64 + dx) << 8) : 0;
        u32x4 kp = *(const u32x4*)(qk + nbase + off + 64);
        float p = 0.f;
        #pragma unroll
        for (int i = 0; i < 4; ++i) {
            p = fmaf(q[2*i],   blo(kp[i]), p);
            p = fmaf(q[2*i+1], bhi(kp[i]), p);
        }
        p += __shfl_xor(p, 1);       // head = 16ch = 2 lanes
        al[e] = valid ? p * 0.25f : -1e30f;
        mx = fmaxf(mx, al[e]);
    }
    float s = 0.f;
    #pragma unroll
    for (int e = 0; e < 9; ++e) { al[e] = __expf(al[e] - mx); s += al[e]; }

    float o[8] = {0.f, 0.f, 0.f, 0.f, 0.f, 0.f, 0.f, 0.f};
    #pragma unroll
    for (int e = 0; e < 9; ++e) {
        const int dy = e / 3 - 1, dx = e % 3 - 1;
        const bool valid = (unsigned)(y + dy) < 64u && (unsigned)(x + dx) < 64u;
        const int off = valid ? ((dy * 64 + dx) << 8) : 0;
        u32x4 vp = *(const u32x4*)(qk + nbase + off + 128);
        const float a = al[e];
        #pragma unroll
        for (int i = 0; i < 4; ++i) {
            o[2*i]   = fmaf(a, blo(vp[i]), o[2*i]);
            o[2*i+1] = fmaf(a, bhi(vp[i]), o[2*i+1]);
        }
    }
    const float r = __fdividef(1.0f, s + 1e-16f);
    u32x4 sp = *(const u32x4*)(qk + nbase + 192);
    u32x4 res;
    #pragma unroll
    for (int i = 0; i < 4; ++i) {
        float h0 = gelu_f(fmaf(o[2*i],   r, blo(sp[i])));
        float h1 = gelu_f(fmaf(o[2*i+1], r, bhi(sp[i])));
        res[i] = packbf(h0, h1);
    }
    *(u32x4*)((u32*)h + (n << 6) + l16 * 4) = res;
}

// ---------------- attention layer 2: heads=1, d=64, 8ch/lane ----------------
// qkvs row = 128 u32 (Q 0..31, K 32..63, V 64..95, S 96..127); out -> xc cols 64..127
__global__ __launch_bounds__(256)
void attn2_kernel(const u16* __restrict__ qkvs, u16* __restrict__ xc) {
    const int tid = threadIdx.x;
    const int l8 = tid & 7;
    const int n = blockIdx.x * 32 + (tid >> 3);
    const int y = (n >> 6) & 63, x = n & 63;
    const u32* qk = (const u32*)qkvs;
    const int nbase = (n << 7) + l8 * 4;

    u32x4 qp = *(const u32x4*)(qk + nbase);
    float q[8];
    #pragma unroll
    for (int i = 0; i < 4; ++i) { q[2*i] = blo(qp[i]); q[2*i+1] = bhi(qp[i]); }

    float al[9];
    float mx = -1e30f;
    #pragma unroll
    for (int e = 0; e < 9; ++e) {
        const int dy = e / 3 - 1, dx = e % 3 - 1;
        const bool valid = (unsigned)(y + dy) < 64u && (unsigned)(x + dx) < 64u;
        const int off = valid ? ((dy * 64 + dx) << 7) : 0;
        u32x4 kp = *(const u32x4*)(qk + nbase + off + 32);
        float p = 0.f;
        #pragma unroll
        for (int i = 0; i < 4; ++i) {
            p = fmaf(q[2*i],   blo(kp[i]), p);
            p = fmaf(q[2*i+1], bhi(kp[i]), p);
        }
        p += __shfl_xor(p, 1);
        p += __shfl_xor(p, 2);
        p += __shfl_xor(p, 4);       // head = 64ch = 8 lanes
        al[e] = valid ? p * 0.125f : -1e30f;
        mx = fmaxf(mx, al[e]);
    }
    float s = 0.f;
    #pragma unroll
    for (int e = 0; e < 9; ++e) { al[e] = __expf(al[e] - mx); s += al[e]; }

    float o[8] = {0.f, 0.f, 0.f, 0.f, 0.f, 0.f, 0.f, 0.f};
    #pragma unroll
    for (int e = 0; e < 9; ++e) {
        const int dy = e / 3 - 1, dx = e % 3 - 1;
        const bool valid = (unsigned)(y + dy) < 64u && (unsigned)(x + dx) < 64u;
        const int off = valid ? ((dy * 64 + dx) << 7) : 0;
        u32x4 vp = *(const u32x4*)(qk + nbase + off + 64);
        const float a = al[e];
        #pragma unroll
        for (int i = 0; i < 4; ++i) {
            o[2*i]   = fmaf(a, blo(vp[i]), o[2*i]);
            o[2*i+1] = fmaf(a, bhi(vp[i]), o[2*i+1]);
        }
    }
    const float r = __fdividef(1.0f, s + 1e-16f);
    u32x4 sp = *(const u32x4*)(qk + nbase + 96);
    u32x4 res;
    #pragma unroll
    for (int i = 0; i < 4; ++i) {
        float h0 = gelu_f(fmaf(o[2*i],   r, blo(sp[i])));
        float h1 = gelu_f(fmaf(o[2*i+1], r, bhi(sp[i])));
        res[i] = packbf(h0, h1);
    }
    *(u32x4*)((u32*)xc + (n << 6) + 32 + l8 * 4) = res;
}

// ---------------- host launcher ----------------
extern "C" void kernel_launch(void* const* d_in, const int* in_sizes, int n_in,
                              void* d_out, int out_size, void* d_ws, size_t ws_size,
                              hipStream_t stream) {
    const float* x   = (const float*)d_in[0];
    const float* cW1 = (const float*)d_in[1];
    const float* cb1 = (const float*)d_in[2];
    const float* cW2 = (const float*)d_in[3];
    const float* cb2 = (const float*)d_in[4];
    const float* q1W = (const float*)d_in[5];
    const float* q1b = (const float*)d_in[6];
    const float* k1W = (const float*)d_in[7];
    const float* k1b = (const float*)d_in[8];
    const float* v1W = (const float*)d_in[9];
    const float* v1b = (const float*)d_in[10];
    const float* s1W = (const float*)d_in[11];
    const float* s1b = (const float*)d_in[12];
    const float* q2W = (const float*)d_in[13];
    const float* q2b = (const float*)d_in[14];
    const float* k2W = (const float*)d_in[15];
    const float* k2b = (const float*)d_in[16];
    const float* v2W = (const float*)d_in[17];
    const float* v2b = (const float*)d_in[18];
    const float* s2W = (const float*)d_in[19];
    const float* s2b = (const float*)d_in[20];
    const float* fW1 = (const float*)d_in[21];
    const float* fb1 = (const float*)d_in[22];
    const float* fW2 = (const float*)d_in[23];
    const float* fb2 = (const float*)d_in[24];

    char* ws = (char*)d_ws;
    float* sig  = (float*)(ws + SIG);
    float* b1   = (float*)(ws + B1OFF);
    float* b2   = (float*)(ws + B2OFF);
    u16* wc1    = (u16*)(ws + WC1);
    u16* wc2    = (u16*)(ws + WC2);
    u16* wf1    = (u16*)(ws + WF1);
    u16* wf2    = (u16*)(ws + WF2);
    u16* wp1    = (u16*)(ws + WP1);
    u16* wp2    = (u16*)(ws + WP2);
    u16* xb     = (u16*)(ws + XB);
    u16* hbuf   = (u16*)(ws + HBUF);
    u16* qkvs2  = (u16*)(ws + QKVS2);
    u16* xc     = (u16*)(ws + XC);
    u16* qkvs1  = (u16*)(ws + QKVS1);
    u16* y1     = (u16*)(ws + Y1);
    u16* tbuf   = (u16*)(ws + TBUF);
    float* gram = (float*)(ws + GRAM);
    float* out  = (float*)d_out;

    gram_kernel<<<160, 256, 0, stream>>>(cW1, cW2, fW1, fW2, gram);
    power_kernel<<<4, 256, 0, stream>>>(gram, sig);
    prep_conv_w<<<dim3(576, 4), 256, 0, stream>>>(cW1, cW2, fW1, fW2, sig,
                                                  wc1, wc2, wf1, wf2);
    prep_proj<<<260, 256, 0, stream>>>(q1W, k1W, v1W, s1W, q2W, k2W, v2W, s2W,
                                       q1b, k1b, v1b, s1b, q2b, k2b, v2b, s2b,
                                       wp1, wp2, b1, b2);
    convert_x<<<1024, 256, 0, stream>>>(x, xb);

    // proj1: [N][64] x [512][64]^T -> qkvs1 [N][512]
    mm_kernel<1, 64, 128, 0><<<dim3(1024, 4), 256, 0, stream>>>(
        xb, wp1, b1, qkvs1, 512, 0, 0);
    attn1_kernel<<<NPIX / 16, 256, 0, stream>>>(qkvs1, hbuf);
    // proj2: [N][128] x [256][128]^T -> qkvs2 [N][256]
    mm_kernel<1, 128, 128, 0><<<dim3(1024, 2), 256, 0, stream>>>(
        hbuf, wp2, b2, qkvs2, 256, 0, 0);
    attn2_kernel<<<NPIX / 32, 256, 0, stream>>>(qkvs2, xc);

    // conv1: im2col(xb, C=64) x [128][576]^T -> y1 [N][128], gelu
    mm_kernel<9, 64, 128, 0><<<dim3(1024, 1), 256, 0, stream>>>(
        xb, wc1, cb1, y1, 128, 0, 1);
    // conv2: im2col(y1, C=128) x [64][1152]^T -> xc cols 0..63, gelu
    mm_kernel<9, 128, 64, 0><<<dim3(1024, 1), 256, 0, stream>>>(
        y1, wc2, cb2, xc, 128, 0, 1);
    // conv3: im2col(xc, C=128) x [128][1152]^T -> t [N][128], gelu
    mm_kernel<9, 128, 128, 0><<<dim3(1024, 1), 256, 0, stream>>>(
        xc, wf1, fb1, tbuf, 128, 0, 1);
    // conv4: im2col(t, C=128) x [64][1152]^T -> out f32 NCHW, gelu
    mm_kernel<9, 128, 64, 1><<<dim3(1024, 1), 256, 0, stream>>>(
        tbuf, wf2, fb2, out, 0, 0, 1);
}